// Round 4
// baseline (4531.536 us; speedup 1.0000x reference)
//
#include <hip/hip_runtime.h>
#include <hip/hip_bf16.h>
#include <math.h>

// Problem constants
#define Bn 2
#define Tn 2048
#define En 1024
#define Hn 16
#define DHn 64
#define DFFn 4096
#define Mn (Bn*Tn)   // 4096 rows

typedef __hip_bfloat16 bf16;

__device__ __forceinline__ float cvt(float v) { return v; }
__device__ __forceinline__ float cvt(bf16 v)  { return __bfloat162float(v); }

// ---------------- LayerNorm: one block per row of E=1024 ---------------------
// Input fp32 (x or X1). Params fp32. Output bf16.
template<typename AT>
__global__ __launch_bounds__(256)
void ln_kernel(const AT* __restrict__ x, const float* __restrict__ g,
               const float* __restrict__ b, bf16* __restrict__ out) {
    const int row = blockIdx.x;
    const int tid = threadIdx.x;
    const AT* xp = x + (size_t)row * En;
    float v[4];
    float s = 0.f, sq = 0.f;
#pragma unroll
    for (int i = 0; i < 4; i++) {
        v[i] = cvt(xp[tid + i * 256]);
        s += v[i];
        sq += v[i] * v[i];
    }
    __shared__ float rs[256], rq[256];
    rs[tid] = s; rq[tid] = sq;
    __syncthreads();
    for (int st = 128; st > 0; st >>= 1) {
        if (tid < st) { rs[tid] += rs[tid + st]; rq[tid] += rq[tid + st]; }
        __syncthreads();
    }
    const float mu  = rs[0] * (1.0f / En);
    const float var = rq[0] * (1.0f / En) - mu * mu;
    const float inv = rsqrtf(var + 1e-5f);
#pragma unroll
    for (int i = 0; i < 4; i++) {
        const int c = tid + i * 256;
        out[(size_t)row * En + c] = __float2bfloat16(
            (v[i] - mu) * inv * g[c] + b[c]);
    }
}

// ---------------- Tiled GEMM: C[4096,Nd] = A[4096,Kd] @ W[Kd,Nd] -------------
// A: bf16 (internal activations, ld=Kd). W/bias: fp32 (model weights, ld=Wld).
// RES_MODE: 0 none / 1 fp32 residual (ld=Nd). OUT_MODE: 0 bf16 / 1 fp32.
#define BM 64
#define BN 64
#define BK 16

template<int HAS_BIAS, int RELU, int RES_MODE, int OUT_MODE>
__global__ __launch_bounds__(256)
void gemm_kernel(const bf16* __restrict__ A, const float* __restrict__ W,
                 const float* __restrict__ bias, const float* __restrict__ res,
                 void* __restrict__ Cout, int Nd, int Kd, int Wld) {
    __shared__ float As[BK][BM];
    __shared__ float Bs[BK][BN];
    const int tid = threadIdx.x;
    const int tx = tid & 15;        // N direction
    const int ty = tid >> 4;        // M direction
    const int arow0 = blockIdx.y * BM;
    const int bcol0 = blockIdx.x * BN;

    float acc[4][4] = {};

    for (int kt = 0; kt < Kd; kt += BK) {
#pragma unroll
        for (int i = 0; i < 4; i++) {
            const int idx = tid + i * 256;
            const int r = idx >> 4, c = idx & 15;
            As[c][r] = __bfloat162float(A[(size_t)(arow0 + r) * Kd + kt + c]);
        }
#pragma unroll
        for (int i = 0; i < 4; i++) {
            const int idx = tid + i * 256;
            const int r = idx >> 6, c = idx & 63;
            Bs[r][c] = W[(size_t)(kt + r) * Wld + bcol0 + c];
        }
        __syncthreads();
#pragma unroll
        for (int kk = 0; kk < BK; kk++) {
            float av[4], bv[4];
#pragma unroll
            for (int i = 0; i < 4; i++) av[i] = As[kk][ty * 4 + i];
#pragma unroll
            for (int j = 0; j < 4; j++) bv[j] = Bs[kk][tx * 4 + j];
#pragma unroll
            for (int i = 0; i < 4; i++)
#pragma unroll
                for (int j = 0; j < 4; j++) acc[i][j] += av[i] * bv[j];
        }
        __syncthreads();
    }

#pragma unroll
    for (int i = 0; i < 4; i++) {
        const int m = arow0 + ty * 4 + i;
#pragma unroll
        for (int j = 0; j < 4; j++) {
            const int n = bcol0 + tx * 4 + j;
            float c = acc[i][j];
            if (HAS_BIAS) c += bias[n];
            if (RELU) c = fmaxf(c, 0.f);
            if (RES_MODE == 1) c += res[(size_t)m * Nd + n];
            if (OUT_MODE == 1) ((float*)Cout)[(size_t)m * Nd + n] = c;
            else               ((bf16*)Cout)[(size_t)m * Nd + n] = __float2bfloat16(c);
        }
    }
}

// ---------------- Causal attention: one block per (q, head, batch) -----------
// Q,K,V bf16 [B,T,H*DH]. O may alias Q: only block (iq,hh,bb) reads that Q
// slice, and the read precedes the write.
__global__ __launch_bounds__(256)
void attn_kernel(const bf16* __restrict__ Q, const bf16* __restrict__ K,
                 const bf16* __restrict__ V, bf16* __restrict__ O) {
    const int iq = blockIdx.x;
    const int hh = blockIdx.y;
    const int bb = blockIdx.z;
    const int tid = threadIdx.x;
    const float scale = 0.03125f;  // E^-0.5 (ref scales by full embd dim 1024)

    __shared__ __align__(16) float qv[DHn];
    __shared__ float sc[Tn];
    __shared__ float red[256];
    __shared__ float part[4][DHn];

    const size_t qoff = ((size_t)(bb * Tn + iq)) * En + hh * DHn;
    if (tid < DHn) qv[tid] = __bfloat162float(Q[qoff + tid]);
    __syncthreads();

    float lmax = -INFINITY;
    for (int k = tid; k <= iq; k += 256) {
        const __hip_bfloat162* k2 =
            (const __hip_bfloat162*)(K + ((size_t)(bb * Tn + k)) * En + hh * DHn);
        float s = 0.f;
#pragma unroll
        for (int d = 0; d < DHn / 2; d++) {
            float2 kk = __bfloat1622float2(k2[d]);
            s += qv[2 * d] * kk.x + qv[2 * d + 1] * kk.y;
        }
        s *= scale;
        sc[k] = s;
        lmax = fmaxf(lmax, s);
    }
    red[tid] = lmax;
    __syncthreads();
    for (int st = 128; st > 0; st >>= 1) {
        if (tid < st) red[tid] = fmaxf(red[tid], red[tid + st]);
        __syncthreads();
    }
    const float gmax = red[0];
    __syncthreads();

    float lsum = 0.f;
    for (int k = tid; k <= iq; k += 256) {
        const float p = expf(sc[k] - gmax);
        sc[k] = p;
        lsum += p;
    }
    red[tid] = lsum;
    __syncthreads();
    for (int st = 128; st > 0; st >>= 1) {
        if (tid < st) red[tid] += red[tid + st];
        __syncthreads();
    }
    const float gsum = red[0];   // >= 1
    __syncthreads();

    const int d = tid & 63;
    const int ch = tid >> 6;
    float acc = 0.f;
    for (int k = ch; k <= iq; k += 4)
        acc += sc[k] * __bfloat162float(V[((size_t)(bb * Tn + k)) * En + hh * DHn + d]);
    part[ch][d] = acc;
    __syncthreads();
    if (tid < DHn) {
        const float o = (part[0][tid] + part[1][tid] + part[2][tid] + part[3][tid]) / gsum;
        O[((size_t)(bb * Tn + iq)) * En + hh * DHn + tid] = __float2bfloat16(o);
    }
}

// ---------------- Launcher ---------------------------------------------------
// Inputs: fp32 (reference dtypes). Output: fp32 [B,T,E] (reference output dtype).
extern "C" void kernel_launch(void* const* d_in, const int* in_sizes, int n_in,
                              void* d_out, int out_size, void* d_ws, size_t ws_size,
                              hipStream_t stream) {
    const float* x   = (const float*)d_in[0];
    const float* Wq  = (const float*)d_in[1];
    const float* Wk  = (const float*)d_in[2];
    const float* Wv  = (const float*)d_in[3];
    const float* Wo  = (const float*)d_in[4];
    const float* bo  = (const float*)d_in[5];
    const float* W1  = (const float*)d_in[6];
    const float* b1  = (const float*)d_in[7];
    const float* W2  = (const float*)d_in[8];
    const float* b2  = (const float*)d_in[9];
    const float* g1  = (const float*)d_in[10];
    const float* be1 = (const float*)d_in[11];
    const float* g2  = (const float*)d_in[12];
    const float* be2 = (const float*)d_in[13];

    // Workspace (40 MB):
    //   [ 0, 8M): Q bf16 -> attention O (in place)
    //   [ 8,16M): K bf16 -> F1 chunk [4096,1024] bf16 (K dead after attn)
    //   [16,24M): V bf16
    //   [24,40M): X1 fp32 [4096,1024]
    // h (bf16, 8 MB) lives in d_out (fp32 out buffer, 16 MB); dead before the
    // final fp32 store overwrites d_out.
    char* wsb = (char*)d_ws;
    const size_t SB = (size_t)Mn * En * sizeof(bf16);   // 8 MB
    bf16*  Qb = (bf16*)(wsb);
    bf16*  Kb = (bf16*)(wsb + SB);
    bf16*  Vb = (bf16*)(wsb + 2 * SB);
    float* X1 = (float*)(wsb + 3 * SB);
    bf16*  F1 = Kb;
    bf16*  h  = (bf16*)d_out;

    const int quarter = DFFn / 4;                       // 1024
    dim3 gE(En / BN, Mn / BM);

    // 1. h = LN(x, g1, be1)
    ln_kernel<float><<<Mn, 256, 0, stream>>>(x, g1, be1, h);

    // 2-4. Q/K/V = h @ W{q,k,v}   (bf16 out)
    gemm_kernel<0,0,0,0><<<gE, 256, 0, stream>>>(h, Wq, nullptr, nullptr, Qb, En, En, En);
    gemm_kernel<0,0,0,0><<<gE, 256, 0, stream>>>(h, Wk, nullptr, nullptr, Kb, En, En, En);
    gemm_kernel<0,0,0,0><<<gE, 256, 0, stream>>>(h, Wv, nullptr, nullptr, Vb, En, En, En);

    // 5. O = causal_softmax(Q K^T * E^-0.5) V   (in place over Q)
    attn_kernel<<<dim3(Tn, Hn, Bn), 256, 0, stream>>>(Qb, Kb, Vb, Qb);

    // 6. X1 = x + O @ Wo + bo   (fp32)
    gemm_kernel<1,0,1,1><<<gE, 256, 0, stream>>>(Qb, Wo, bo, x, X1, En, En, En);

    // 7. h2 = LN(X1, g2, be2)   (bf16, into d_out scratch)
    ln_kernel<float><<<Mn, 256, 0, stream>>>(X1, g2, be2, h);

    // 8-9. FFN in 4 chunks of DFF/4 = 1024:
    //      F1 = relu(h2 @ W1q + b1q) (bf16);  X1 += F1 @ W2q (fp32, in place);
    //      last chunk adds b2 and writes fp32 d_out.
    for (int q = 0; q < 4; q++) {
        const size_t wc = (size_t)q * quarter;
        gemm_kernel<1,1,0,0><<<gE, 256, 0, stream>>>(
            h, W1 + wc, b1 + wc, nullptr, F1, quarter, En, DFFn);
        if (q < 3) {
            gemm_kernel<0,0,1,1><<<gE, 256, 0, stream>>>(
                F1, W2 + wc * En, nullptr, X1, X1, En, quarter, En);
        } else {
            gemm_kernel<1,0,1,1><<<gE, 256, 0, stream>>>(
                F1, W2 + wc * En, b2, X1, d_out, En, quarter, En);
        }
    }
}

// Round 6
// 679.493 us; speedup vs baseline: 6.6690x; 6.6690x over previous
//
#include <hip/hip_runtime.h>
#include <hip/hip_bf16.h>
#include <math.h>

// Problem constants
#define Bn 2
#define Tn 2048
#define En 1024
#define Hn 16
#define DHn 64
#define DFFn 4096
#define Mn (Bn*Tn)   // 4096 rows
#define QKVLD 3072   // fused QKV leading dim

typedef __hip_bfloat16 bf16;
typedef unsigned short u16;
typedef __attribute__((ext_vector_type(8))) short short8;
typedef __attribute__((ext_vector_type(4))) float f32x4;

__device__ __forceinline__ u16 f2bf(float f) {
    bf16 h = __float2bfloat16(f);
    u16 u; __builtin_memcpy(&u, &h, 2); return u;
}

// ---------------- LayerNorm: one block per row of E=1024 ---------------------
__global__ __launch_bounds__(256)
void ln_kernel(const float* __restrict__ x, const float* __restrict__ g,
               const float* __restrict__ b, u16* __restrict__ out) {
    const int row = blockIdx.x;
    const int tid = threadIdx.x;
    const float* xp = x + (size_t)row * En;
    float v[4];
    float s = 0.f, sq = 0.f;
#pragma unroll
    for (int i = 0; i < 4; i++) {
        v[i] = xp[tid + i * 256];
        s += v[i];
        sq += v[i] * v[i];
    }
    __shared__ float rs[256], rq[256];
    rs[tid] = s; rq[tid] = sq;
    __syncthreads();
    for (int st = 128; st > 0; st >>= 1) {
        if (tid < st) { rs[tid] += rs[tid + st]; rq[tid] += rq[tid + st]; }
        __syncthreads();
    }
    const float mu  = rs[0] * (1.0f / En);
    const float var = rq[0] * (1.0f / En) - mu * mu;
    const float inv = rsqrtf(var + 1e-5f);
#pragma unroll
    for (int i = 0; i < 4; i++) {
        const int c = tid + i * 256;
        out[(size_t)row * En + c] = f2bf((v[i] - mu) * inv * g[c] + b[c]);
    }
}

// ---------------- MFMA GEMM: C[4096,N] = A[4096,K](bf16) @ W[K,N](fp32) ------
// 128x128 tile, BK=32, 256 thr = 4 waves, each wave 64x64 (4x4 of 16x16x32).
// LDS rows padded to 40 shorts (80 B: b128-aligned, 2-way banks = free, m136).
// W converted fp32->bf16 during staging. Epilogue: bias/relu/residual.
template<int HAS_BIAS, int RELU, int HAS_RES, int OUT_F32>
__global__ __launch_bounds__(256)
void mfma_gemm(const u16* __restrict__ A, int ldA,
               const float* __restrict__ W, int ldW,
               const float* __restrict__ bias,
               const float* __restrict__ res,
               void* __restrict__ Cout, int ldC, int Kd) {
    __shared__ __align__(16) u16 As[128 * 40];
    __shared__ __align__(16) u16 Bs[128 * 40];
    const int tid  = threadIdx.x;
    const int lane = tid & 63, wv = tid >> 6;
    const int quad = lane >> 4, l16 = lane & 15;
    const int m0 = blockIdx.y * 128, n0 = blockIdx.x * 128;
    const int rw = (wv >> 1) * 64, cw = (wv & 1) * 64;

    f32x4 acc[4][4] = {};
    const int ar = tid >> 2, acg = tid & 3;   // A staging: row, 16B col-group (BK=32: 4 groups)
    const int bn = tid & 127, bkg = tid >> 7; // B staging: col, k-subgroup

    for (int kt = 0; kt < Kd; kt += 32) {
        // A tile 128x32 bf16 (full coverage: 256 thr x 2 uint4 = 4096 shorts)
        *(uint4*)&As[ar * 40 + acg * 8] =
            *(const uint4*)&A[(size_t)(m0 + ar) * ldA + kt + acg * 8];
        *(uint4*)&As[(ar + 64) * 40 + acg * 8] =
            *(const uint4*)&A[(size_t)(m0 + ar + 64) * ldA + kt + acg * 8];
        // W tile 32x128 fp32 -> Bs[n][k] bf16 (transposed; coalesced in n)
#pragma unroll
        for (int g = 0; g < 4; g++) {
            const int k0l = (bkg + 2 * g) * 4;
            ushort4 pk;
            pk.x = f2bf(W[(size_t)(kt + k0l + 0) * ldW + n0 + bn]);
            pk.y = f2bf(W[(size_t)(kt + k0l + 1) * ldW + n0 + bn]);
            pk.z = f2bf(W[(size_t)(kt + k0l + 2) * ldW + n0 + bn]);
            pk.w = f2bf(W[(size_t)(kt + k0l + 3) * ldW + n0 + bn]);
            *(ushort4*)&Bs[bn * 40 + k0l] = pk;
        }
        __syncthreads();
        short8 af[4], bfg[4];
#pragma unroll
        for (int i = 0; i < 4; i++)
            af[i] = *(const short8*)&As[(rw + i * 16 + l16) * 40 + quad * 8];
#pragma unroll
        for (int j = 0; j < 4; j++)
            bfg[j] = *(const short8*)&Bs[(cw + j * 16 + l16) * 40 + quad * 8];
#pragma unroll
        for (int i = 0; i < 4; i++)
#pragma unroll
            for (int j = 0; j < 4; j++)
                acc[i][j] = __builtin_amdgcn_mfma_f32_16x16x32_bf16(
                    af[i], bfg[j], acc[i][j], 0, 0, 0);
        __syncthreads();
    }

    // Epilogue. C/D layout: row = quad*4+r, col = l16 (m89-verified).
#pragma unroll
    for (int i = 0; i < 4; i++) {
#pragma unroll
        for (int r = 0; r < 4; r++) {
            const int gm = m0 + rw + i * 16 + quad * 4 + r;
#pragma unroll
            for (int j = 0; j < 4; j++) {
                const int gn = n0 + cw + j * 16 + l16;
                float c = acc[i][j][r];
                if (HAS_BIAS) c += bias[gn];
                if (RELU) c = fmaxf(c, 0.f);
                if (HAS_RES) c += res[(size_t)gm * ldC + gn];
                if (OUT_F32) ((float*)Cout)[(size_t)gm * ldC + gn] = c;
                else         ((u16*)Cout)[(size_t)gm * ldC + gn] = f2bf(c);
            }
        }
    }
}

// ---------------- Flash attention (MFMA, online softmax) ---------------------
// QKV [4096][3072] bf16: Q @ col 0, K @ 1024, V @ 2048, per-head slices of 64.
// Block = 256 thr (4 waves); processes q-tiles {x, 31-x} (uniform 33 k-iters).
// Wave w owns q-rows w*16..w*16+15 of the 64-row tile. O in-place over Q.
__global__ __launch_bounds__(256)
void flash_attn(u16* __restrict__ QKV) {
    const int hh = blockIdx.y, bb = blockIdx.z;
    const int tid  = threadIdx.x;
    const int lane = tid & 63, wv = tid >> 6;
    const int quad = lane >> 4, l16 = lane & 15;

    __shared__ __align__(16) u16 Qs[64 * 72];       // 144 B rows (9*16)
    __shared__ __align__(16) u16 Ks[64 * 72];
    __shared__ __align__(16) u16 Vt[64 * 72];       // V transposed: Vt[dh][key]
    __shared__ __align__(16) u16 Ps[4][16 * 72];    // per-wave P strip

    const size_t rowbase = (size_t)(bb * Tn) * QKVLD;
    const int sr = tid >> 2, scg = tid & 3;    // staging: row 0..63, col-group 0..3
    const int vd = tid & 63, vrb = tid >> 6;   // V-transpose staging

    for (int qsel = 0; qsel < 2; qsel++) {
        const int qt = qsel ? (31 - blockIdx.x) : blockIdx.x;

        // stage Q tile 64x64 (2 uint4/thread: cols scg*8 and (scg+4)*8)
        __syncthreads();
        {
            const size_t qbase = rowbase + (size_t)(qt * 64 + sr) * QKVLD + hh * 64;
            *(uint4*)&Qs[sr * 72 + scg * 8]       = *(const uint4*)&QKV[qbase + scg * 8];
            *(uint4*)&Qs[sr * 72 + (scg + 4) * 8] = *(const uint4*)&QKV[qbase + (scg + 4) * 8];
        }
        __syncthreads();
        short8 qf[2];
        qf[0] = *(const short8*)&Qs[(wv * 16 + l16) * 72 + quad * 8];
        qf[1] = *(const short8*)&Qs[(wv * 16 + l16) * 72 + 32 + quad * 8];

        f32x4 oacc[4] = {};
        float mrow[4] = {-INFINITY, -INFINITY, -INFINITY, -INFINITY};
        float lrow[4] = {};

        for (int kt = 0; kt <= qt; kt++) {
            __syncthreads();   // prior iteration's Ks/Vt readers done
            // stage K tile 64x64 (full coverage) + V tile transposed
            {
                const size_t kbase = rowbase + (size_t)(kt * 64 + sr) * QKVLD + 1024 + hh * 64;
                *(uint4*)&Ks[sr * 72 + scg * 8]       = *(const uint4*)&QKV[kbase + scg * 8];
                *(uint4*)&Ks[sr * 72 + (scg + 4) * 8] = *(const uint4*)&QKV[kbase + (scg + 4) * 8];
            }
#pragma unroll
            for (int i = 0; i < 16; i++) {
                const int r2 = vrb * 16 + i;
                Vt[vd * 72 + r2] =
                    QKV[rowbase + (size_t)(kt * 64 + r2) * QKVLD + 2048 + hh * 64 + vd];
            }
            __syncthreads();

            // S strip (16 q-rows x 64 keys) = Q Ktile^T
            f32x4 sacc[4] = {};
#pragma unroll
            for (int ks = 0; ks < 2; ks++) {
#pragma unroll
                for (int j = 0; j < 4; j++) {
                    short8 bk = *(const short8*)&Ks[(j * 16 + l16) * 72 + ks * 32 + quad * 8];
                    sacc[j] = __builtin_amdgcn_mfma_f32_16x16x32_bf16(qf[ks], bk, sacc[j], 0, 0, 0);
                }
            }

            // scale + causal mask + per-row online softmax
            float p[4][4], tmax[4];
            const int qrow0 = qt * 64 + wv * 16 + quad * 4;  // + r
            const int kcol0 = kt * 64 + l16;                 // + j*16
#pragma unroll
            for (int r = 0; r < 4; r++) {
                float mx = -INFINITY;
#pragma unroll
                for (int j = 0; j < 4; j++) {
                    float s = sacc[j][r] * 0.03125f;          // E^-0.5
                    if (kcol0 + j * 16 > qrow0 + r) s = -INFINITY;
                    p[j][r] = s;
                    mx = fmaxf(mx, s);
                }
                tmax[r] = mx;
            }
#pragma unroll
            for (int m = 1; m < 16; m <<= 1)
#pragma unroll
                for (int r = 0; r < 4; r++)
                    tmax[r] = fmaxf(tmax[r], __shfl_xor(tmax[r], m));
            float alpha[4], psum[4];
#pragma unroll
            for (int r = 0; r < 4; r++) {
                const float mnew = fmaxf(mrow[r], tmax[r]);
                alpha[r] = expf(mrow[r] - mnew);
                mrow[r] = mnew;
                float s = 0.f;
#pragma unroll
                for (int j = 0; j < 4; j++) {
                    const float e = expf(p[j][r] - mnew);
                    p[j][r] = e;
                    s += e;
                }
                psum[r] = s;
            }
#pragma unroll
            for (int m = 1; m < 16; m <<= 1)
#pragma unroll
                for (int r = 0; r < 4; r++)
                    psum[r] += __shfl_xor(psum[r], m);
#pragma unroll
            for (int r = 0; r < 4; r++) {
                lrow[r] = lrow[r] * alpha[r] + psum[r];
#pragma unroll
                for (int jd = 0; jd < 4; jd++) oacc[jd][r] *= alpha[r];
            }

            // P (C-layout) -> LDS bf16 row-major, then read as A-operand.
#pragma unroll
            for (int j = 0; j < 4; j++)
#pragma unroll
                for (int r = 0; r < 4; r++)
                    Ps[wv][(quad * 4 + r) * 72 + j * 16 + l16] = f2bf(p[j][r]);
            // cross-lane LDS round-trip within the wave: force write completion
            asm volatile("s_waitcnt lgkmcnt(0)" ::: "memory");

            // O strip += P @ Vtile   (B-operand from Vt[dh][key])
#pragma unroll
            for (int ks = 0; ks < 2; ks++) {
                short8 pf = *(const short8*)&Ps[wv][l16 * 72 + ks * 32 + quad * 8];
#pragma unroll
                for (int jd = 0; jd < 4; jd++) {
                    short8 vf = *(const short8*)&Vt[(jd * 16 + l16) * 72 + ks * 32 + quad * 8];
                    oacc[jd] = __builtin_amdgcn_mfma_f32_16x16x32_bf16(pf, vf, oacc[jd], 0, 0, 0);
                }
            }
        }

        // write O over Q slice (only this block touches these rows+cols)
#pragma unroll
        for (int r = 0; r < 4; r++) {
            const float inv = 1.0f / lrow[r];
            const int gq = qt * 64 + wv * 16 + quad * 4 + r;
#pragma unroll
            for (int jd = 0; jd < 4; jd++)
                QKV[rowbase + (size_t)gq * QKVLD + hh * 64 + jd * 16 + l16] =
                    f2bf(oacc[jd][r] * inv);
        }
    }
}

// ---------------- Launcher ---------------------------------------------------
extern "C" void kernel_launch(void* const* d_in, const int* in_sizes, int n_in,
                              void* d_out, int out_size, void* d_ws, size_t ws_size,
                              hipStream_t stream) {
    const float* x   = (const float*)d_in[0];
    const float* Wq  = (const float*)d_in[1];
    const float* Wk  = (const float*)d_in[2];
    const float* Wv  = (const float*)d_in[3];
    const float* Wo  = (const float*)d_in[4];
    const float* bo  = (const float*)d_in[5];
    const float* W1  = (const float*)d_in[6];
    const float* b1  = (const float*)d_in[7];
    const float* W2  = (const float*)d_in[8];
    const float* b2  = (const float*)d_in[9];
    const float* g1  = (const float*)d_in[10];
    const float* be1 = (const float*)d_in[11];
    const float* g2  = (const float*)d_in[12];
    const float* be2 = (const float*)d_in[13];

    // Workspace (40 MB):
    //   [ 0,24M): QKV bf16 [4096][3072]; O overwrites Q cols; F1 [4096][2048]
    //             bf16 (16 MB) reuses this region after attention+O-proj.
    //   [24,40M): X1 fp32 [4096][1024]
    // h (bf16, 8 MB) lives in d_out (16 MB fp32), dead before final store.
    char* wsb = (char*)d_ws;
    u16*   QKV = (u16*)wsb;
    float* X1  = (float*)(wsb + (size_t)Mn * QKVLD * 2);
    u16*   F1  = QKV;
    u16*   h   = (u16*)d_out;

    // 1. h = LN(x, g1, be1)
    ln_kernel<<<Mn, 256, 0, stream>>>(x, g1, be1, h);

    // 2-4. QKV = h @ [Wq|Wk|Wv]  (bf16 out, fused buffer, ldC=3072)
    dim3 gQ(En / 128, Mn / 128);
    mfma_gemm<0,0,0,0><<<gQ, 256, 0, stream>>>(h, En, Wq, En, nullptr, nullptr, QKV,        QKVLD, En);
    mfma_gemm<0,0,0,0><<<gQ, 256, 0, stream>>>(h, En, Wk, En, nullptr, nullptr, QKV + 1024, QKVLD, En);
    mfma_gemm<0,0,0,0><<<gQ, 256, 0, stream>>>(h, En, Wv, En, nullptr, nullptr, QKV + 2048, QKVLD, En);

    // 5. O = causal_softmax(Q K^T * E^-0.5) V   (in place over Q cols)
    flash_attn<<<dim3(16, Hn, Bn), 256, 0, stream>>>(QKV);

    // 6. X1 = x + O @ Wo + bo   (fp32)
    mfma_gemm<1,0,1,1><<<gQ, 256, 0, stream>>>(QKV, QKVLD, Wo, En, bo, x, X1, En, En);

    // 7. h2 = LN(X1, g2, be2)   (into d_out scratch)
    ln_kernel<<<Mn, 256, 0, stream>>>(X1, g2, be2, h);

    // 8-9. FFN in 2 halves of 2048; X1 accumulates in place; final -> d_out fp32
    dim3 gF(2048 / 128, Mn / 128);
    for (int hf = 0; hf < 2; hf++) {
        const float* W1h = W1 + hf * 2048;                 // col offset, ldW=4096
        const float* b1h = b1 + hf * 2048;
        const float* W2h = W2 + (size_t)hf * 2048 * En;    // row offset, ldW=1024

        mfma_gemm<1,1,0,0><<<gF, 256, 0, stream>>>(h, En, W1h, DFFn, b1h, nullptr, F1, 2048, En);
        if (hf == 0)
            mfma_gemm<0,0,1,1><<<gQ, 256, 0, stream>>>(F1, 2048, W2h, En, nullptr, X1, X1, En, 2048);
        else
            mfma_gemm<1,0,1,1><<<gQ, 256, 0, stream>>>(F1, 2048, W2h, En, b2, X1, d_out, En, 2048);
    }
}

// Round 7
// 517.817 us; speedup vs baseline: 8.7512x; 1.3122x over previous
//
#include <hip/hip_runtime.h>
#include <hip/hip_bf16.h>
#include <math.h>

// Problem constants
#define Bn 2
#define Tn 2048
#define En 1024
#define Hn 16
#define DFFn 4096
#define Mn (Bn*Tn)   // 4096 rows
#define QKVLD 3072   // fused QKV leading dim

typedef __hip_bfloat16 bf16;
typedef unsigned short u16;
typedef __attribute__((ext_vector_type(8))) short short8;
typedef __attribute__((ext_vector_type(4))) float f32x4;

typedef __attribute__((address_space(1))) const void cg_void;
typedef __attribute__((address_space(3))) void lds_void;

__device__ __forceinline__ u16 f2bf(float f) {
    bf16 h = __float2bfloat16(f);
    u16 u; __builtin_memcpy(&u, &h, 2); return u;
}

// ---------------- weight transpose+convert: src fp32 [R][C] -> dst bf16 [C][R]
__global__ __launch_bounds__(256)
void transpose_w(const float* __restrict__ src, u16* __restrict__ dst,
                 int R, int C) {
    __shared__ float t[64][65];
    const int r0 = blockIdx.y * 64, c0 = blockIdx.x * 64;
    const int tr = threadIdx.x >> 6, tc = threadIdx.x & 63;
#pragma unroll
    for (int i = 0; i < 16; i++)
        t[tr + i * 4][tc] = src[(size_t)(r0 + tr + i * 4) * C + c0 + tc];
    __syncthreads();
#pragma unroll
    for (int i = 0; i < 16; i++)
        dst[(size_t)(c0 + tr + i * 4) * R + r0 + tc] = f2bf(t[tc][tr + i * 4]);
}

// ---------------- LayerNorm: one block per row of E=1024 ---------------------
__global__ __launch_bounds__(256)
void ln_kernel(const float* __restrict__ x, const float* __restrict__ g,
               const float* __restrict__ b, u16* __restrict__ out) {
    const int row = blockIdx.x;
    const int tid = threadIdx.x;
    const float* xp = x + (size_t)row * En;
    float v[4];
    float s = 0.f, sq = 0.f;
#pragma unroll
    for (int i = 0; i < 4; i++) {
        v[i] = xp[tid + i * 256];
        s += v[i];
        sq += v[i] * v[i];
    }
    __shared__ float rs[256], rq[256];
    rs[tid] = s; rq[tid] = sq;
    __syncthreads();
    for (int st = 128; st > 0; st >>= 1) {
        if (tid < st) { rs[tid] += rs[tid + st]; rq[tid] += rq[tid + st]; }
        __syncthreads();
    }
    const float mu  = rs[0] * (1.0f / En);
    const float var = rq[0] * (1.0f / En) - mu * mu;
    const float inv = rsqrtf(var + 1e-5f);
#pragma unroll
    for (int i = 0; i < 4; i++) {
        const int c = tid + i * 256;
        out[(size_t)row * En + c] = f2bf((v[i] - mu) * inv * g[c] + b[c]);
    }
}

// ---------------- m97-style GEMM: C[4096,N] = A(bf16) @ Wt(bf16 [N][K])^T ----
// TM x 128 tile (TM = 128 or 64), BK=32, 4 waves. global_load_lds width=16
// staging into unpadded [rows][32] LDS (lane-contiguous per m104/m108 rule).
template<int TM, int HAS_BIAS, int RELU, int HAS_RES, int OUT_F32>
__global__ __launch_bounds__(256)
void gemm_bt(const u16* __restrict__ A, int ldA,
             const u16* __restrict__ Wt, int ldW,
             const float* __restrict__ bias, const float* __restrict__ res,
             void* __restrict__ Cout, int ldC, int Kd) {
    constexpr int IF = TM / 32;          // i-frags per wave
    __shared__ __align__(16) u16 As[TM * 32];
    __shared__ __align__(16) u16 Bs[128 * 32];
    const int tid  = threadIdx.x;
    const int lane = tid & 63, wv = tid >> 6;
    const int quad = lane >> 4, l16 = lane & 15;
    const int m0 = blockIdx.y * TM, n0 = blockIdx.x * 128;
    const int rw = (wv >> 1) * (TM / 2), cw = (wv & 1) * 64;
    const int lr = lane >> 2, lc = (lane & 3) * 8;   // staging lane row/colgrp

    f32x4 acc[IF][4] = {};

    for (int kt = 0; kt < Kd; kt += 32) {
        __syncthreads();   // previous iteration's LDS readers done
        // A tile TM x 32: each wave-instr = 16 rows x 64 B, lane L -> L*16 B
#pragma unroll
        for (int t = 0; t < TM / 64; t++) {
            const int row = wv * (TM / 4) + t * 16;
            __builtin_amdgcn_global_load_lds(
                (cg_void*)(const void*)&A[(size_t)(m0 + row + lr) * ldA + kt + lc],
                (lds_void*)(void*)&As[row * 32], 16, 0, 0);
        }
        // B tile 128 x 32 from Wt [N][K]
#pragma unroll
        for (int t = 0; t < 2; t++) {
            const int row = wv * 32 + t * 16;
            __builtin_amdgcn_global_load_lds(
                (cg_void*)(const void*)&Wt[(size_t)(n0 + row + lr) * ldW + kt + lc],
                (lds_void*)(void*)&Bs[row * 32], 16, 0, 0);
        }
        __syncthreads();   // compiler emits vmcnt(0) drain before barrier

        short8 af[IF], bfr[4];
#pragma unroll
        for (int i = 0; i < IF; i++)
            af[i] = *(const short8*)&As[(rw + i * 16 + l16) * 32 + quad * 8];
#pragma unroll
        for (int j = 0; j < 4; j++)
            bfr[j] = *(const short8*)&Bs[(cw + j * 16 + l16) * 32 + quad * 8];
#pragma unroll
        for (int i = 0; i < IF; i++)
#pragma unroll
            for (int j = 0; j < 4; j++)
                acc[i][j] = __builtin_amdgcn_mfma_f32_16x16x32_bf16(
                    af[i], bfr[j], acc[i][j], 0, 0, 0);
    }

    // Epilogue. C/D layout: row = quad*4+r, col = l16 (m89-verified).
#pragma unroll
    for (int i = 0; i < IF; i++) {
#pragma unroll
        for (int r = 0; r < 4; r++) {
            const int gm = m0 + rw + i * 16 + quad * 4 + r;
#pragma unroll
            for (int j = 0; j < 4; j++) {
                const int gn = n0 + cw + j * 16 + l16;
                float c = acc[i][j][r];
                if (HAS_BIAS) c += bias[gn];
                if (RELU) c = fmaxf(c, 0.f);
                if (HAS_RES) c += res[(size_t)gm * ldC + gn];
                if (OUT_F32) ((float*)Cout)[(size_t)gm * ldC + gn] = c;
                else         ((u16*)Cout)[(size_t)gm * ldC + gn] = f2bf(c);
            }
        }
    }
}

// ---------------- Flash attention v2 (MFMA, online softmax, log2 domain) -----
// QKV [4096][3072] bf16: Q@0, K@1024, V@2048, per-head slices of 64.
// One q-tile (64 rows) per block; grid (32, H, B) = 1024 blocks (4/CU).
// Wave w owns q-rows w*16..+15. O written in-place over Q.
__global__ __launch_bounds__(256)
void flash_attn(u16* __restrict__ QKV) {
    const int qt = blockIdx.x;
    const int hh = blockIdx.y, bb = blockIdx.z;
    const int tid  = threadIdx.x;
    const int lane = tid & 63, wv = tid >> 6;
    const int quad = lane >> 4, l16 = lane & 15;

    __shared__ __align__(16) u16 Qs[64 * 80];       // stride 80: 2-way banks on b128
    __shared__ __align__(16) u16 Ks[64 * 80];
    __shared__ __align__(16) u16 Vt[64 * 80];       // [dh][key]
    __shared__ __align__(16) u16 Ps[4][16 * 72];    // per-wave P strip

    const size_t rowbase = (size_t)(bb * Tn) * QKVLD;
    const int sr = tid >> 2, scg = tid & 3;         // Q/K staging
    const int vkey = tid & 63, vw = tid >> 6;       // V staging: lane=key

    // stage Q once
    {
        const size_t qb = rowbase + (size_t)(qt * 64 + sr) * QKVLD + hh * 64;
        *(uint4*)&Qs[sr * 80 + scg * 8]       = *(const uint4*)&QKV[qb + scg * 8];
        *(uint4*)&Qs[sr * 80 + (scg + 4) * 8] = *(const uint4*)&QKV[qb + (scg + 4) * 8];
    }
    __syncthreads();
    short8 qf[2];
    qf[0] = *(const short8*)&Qs[(wv * 16 + l16) * 80 + quad * 8];
    qf[1] = *(const short8*)&Qs[(wv * 16 + l16) * 80 + 32 + quad * 8];

    f32x4 oacc[4] = {};
    float m2[4]   = {-INFINITY, -INFINITY, -INFINITY, -INFINITY};  // log2 domain
    float lrow[4] = {};
    const float SC = 0.03125f * 1.44269504089f;   // E^-0.5 * log2(e)

    for (int kt = 0; kt <= qt; kt++) {
        __syncthreads();   // previous iteration's Ks/Vt readers done
        {   // K tile row-major
            const size_t kb = rowbase + (size_t)(kt * 64 + sr) * QKVLD + 1024 + hh * 64;
            *(uint4*)&Ks[sr * 80 + scg * 8]       = *(const uint4*)&QKV[kb + scg * 8];
            *(uint4*)&Ks[sr * 80 + (scg + 4) * 8] = *(const uint4*)&QKV[kb + (scg + 4) * 8];
        }
        {   // V tile transposed: lane=key -> conflict-free LDS column writes
            const size_t vb = rowbase + (size_t)(kt * 64 + vkey) * QKVLD + 2048 + hh * 64 + vw * 16;
            u16 vtmp[16];
            *(uint4*)&vtmp[0] = *(const uint4*)&QKV[vb];
            *(uint4*)&vtmp[8] = *(const uint4*)&QKV[vb + 8];
#pragma unroll
            for (int u = 0; u < 16; u++)
                Vt[(vw * 16 + u) * 80 + vkey] = vtmp[u];
        }
        __syncthreads();

        // S strip (16 q-rows x 64 keys) = Q Ktile^T
        f32x4 sacc[4] = {};
#pragma unroll
        for (int ks = 0; ks < 2; ks++)
#pragma unroll
            for (int j = 0; j < 4; j++) {
                short8 bk = *(const short8*)&Ks[(j * 16 + l16) * 80 + ks * 32 + quad * 8];
                sacc[j] = __builtin_amdgcn_mfma_f32_16x16x32_bf16(qf[ks], bk, sacc[j], 0, 0, 0);
            }

        // scale into log2 domain (+ causal mask on the diagonal tile only)
        float p[4][4], tmax[4];
        if (kt == qt) {                       // block-uniform branch
            const int qloc = wv * 16 + quad * 4;
#pragma unroll
            for (int r = 0; r < 4; r++) {
                float mx = -INFINITY;
#pragma unroll
                for (int j = 0; j < 4; j++) {
                    float s = sacc[j][r] * SC;
                    if (l16 + j * 16 > qloc + r) s = -INFINITY;
                    p[j][r] = s;
                    mx = fmaxf(mx, s);
                }
                tmax[r] = mx;
            }
        } else {
#pragma unroll
            for (int r = 0; r < 4; r++) {
                float mx = -INFINITY;
#pragma unroll
                for (int j = 0; j < 4; j++) {
                    const float s = sacc[j][r] * SC;
                    p[j][r] = s;
                    mx = fmaxf(mx, s);
                }
                tmax[r] = mx;
            }
        }
#pragma unroll
        for (int m = 1; m < 16; m <<= 1)
#pragma unroll
            for (int r = 0; r < 4; r++)
                tmax[r] = fmaxf(tmax[r], __shfl_xor(tmax[r], m));

        float alpha[4], psum[4];
#pragma unroll
        for (int r = 0; r < 4; r++) {
            const float mnew = fmaxf(m2[r], tmax[r]);
            alpha[r] = exp2f(m2[r] - mnew);   // first iter: exp2(-inf)=0
            m2[r] = mnew;
            float s = 0.f;
#pragma unroll
            for (int j = 0; j < 4; j++) {
                const float e = exp2f(p[j][r] - mnew);
                p[j][r] = e;
                s += e;
            }
            psum[r] = s;
        }
#pragma unroll
        for (int m = 1; m < 16; m <<= 1)
#pragma unroll
            for (int r = 0; r < 4; r++)
                psum[r] += __shfl_xor(psum[r], m);
#pragma unroll
        for (int r = 0; r < 4; r++) {
            lrow[r] = lrow[r] * alpha[r] + psum[r];
#pragma unroll
            for (int jd = 0; jd < 4; jd++) oacc[jd][r] *= alpha[r];
        }

        // P (C-layout) -> LDS row-major, re-read as A-operand
#pragma unroll
        for (int j = 0; j < 4; j++)
#pragma unroll
            for (int r = 0; r < 4; r++)
                Ps[wv][(quad * 4 + r) * 72 + j * 16 + l16] = f2bf(p[j][r]);
        asm volatile("s_waitcnt lgkmcnt(0)" ::: "memory");

        // O strip += P @ Vtile
#pragma unroll
        for (int ks = 0; ks < 2; ks++) {
            short8 pf = *(const short8*)&Ps[wv][l16 * 72 + ks * 32 + quad * 8];
#pragma unroll
            for (int jd = 0; jd < 4; jd++) {
                short8 vf = *(const short8*)&Vt[(jd * 16 + l16) * 80 + ks * 32 + quad * 8];
                oacc[jd] = __builtin_amdgcn_mfma_f32_16x16x32_bf16(pf, vf, oacc[jd], 0, 0, 0);
            }
        }
    }

    // write O over Q slice
#pragma unroll
    for (int r = 0; r < 4; r++) {
        const float inv = 1.0f / lrow[r];
        const int gq = qt * 64 + wv * 16 + quad * 4 + r;
#pragma unroll
        for (int jd = 0; jd < 4; jd++)
            QKV[rowbase + (size_t)gq * QKVLD + hh * 64 + jd * 16 + l16] =
                f2bf(oacc[jd][r] * inv);
    }
}

// ---------------- Launcher ---------------------------------------------------
// Inputs fp32, output fp32 [B,T,E].
extern "C" void kernel_launch(void* const* d_in, const int* in_sizes, int n_in,
                              void* d_out, int out_size, void* d_ws, size_t ws_size,
                              hipStream_t stream) {
    const float* x   = (const float*)d_in[0];
    const float* Wq  = (const float*)d_in[1];
    const float* Wk  = (const float*)d_in[2];
    const float* Wv  = (const float*)d_in[3];
    const float* Wo  = (const float*)d_in[4];
    const float* bo  = (const float*)d_in[5];
    const float* W1  = (const float*)d_in[6];
    const float* b1  = (const float*)d_in[7];
    const float* W2  = (const float*)d_in[8];
    const float* b2  = (const float*)d_in[9];
    const float* g1  = (const float*)d_in[10];
    const float* be1 = (const float*)d_in[11];
    const float* g2  = (const float*)d_in[12];
    const float* be2 = (const float*)d_in[13];

    // Workspace (40 MB):
    //   [ 0,24M): QKV bf16 [4096][3072]; dead after O-proj -> F1 [0,16M),
    //             W2T bf16 [1024][4096] at [16,24M)
    //   [24,40M): X1 fp32 [4096][1024]
    // d_out (16 MB fp32): [0,8M) h bf16; [8,16M) early WqkvT+WoT, late W1T.
    // All d_out scratch is dead before the final fp32 store.
    char* wsb = (char*)d_ws;
    u16*   QKV = (u16*)wsb;
    u16*   F1  = (u16*)wsb;                              // [4096][2048]
    u16*   W2T = (u16*)(wsb + 16u * 1024 * 1024);        // [1024][4096]
    float* X1  = (float*)(wsb + 24u * 1024 * 1024);
    u16*   h     = (u16*)d_out;
    u16*   WT    = (u16*)((char*)d_out + 8u * 1024 * 1024);
    u16*   WqkvT = WT;                                   // [3072][1024]
    u16*   WoT   = WT + 3u * 1024 * 1024;                // [1024][1024]
    u16*   W1T   = WT;                                   // [4096][1024] (late)

    // 0. early weight transposes (fp32 -> bf16, B^T layout)
    transpose_w<<<dim3(16, 16), 256, 0, stream>>>(Wq, WqkvT,                 1024, 1024);
    transpose_w<<<dim3(16, 16), 256, 0, stream>>>(Wk, WqkvT + 1024u * 1024,  1024, 1024);
    transpose_w<<<dim3(16, 16), 256, 0, stream>>>(Wv, WqkvT + 2048u * 1024,  1024, 1024);
    transpose_w<<<dim3(16, 16), 256, 0, stream>>>(Wo, WoT,                   1024, 1024);

    // 1. h = LN(x, g1, be1)
    ln_kernel<<<Mn, 256, 0, stream>>>(x, g1, be1, h);

    // 2. QKV = h @ [Wq|Wk|Wv]  (one fused GEMM, N=3072, 768 blocks)
    gemm_bt<128, 0, 0, 0, 0><<<dim3(24, 32), 256, 0, stream>>>(
        h, En, WqkvT, En, nullptr, nullptr, QKV, QKVLD, En);

    // 3. O = causal_softmax(Q K^T * E^-0.5) V   (in place over Q cols)
    flash_attn<<<dim3(32, Hn, Bn), 256, 0, stream>>>(QKV);

    // 4. X1 = x + O @ Wo + bo   (fp32; TM=64 -> 512 blocks)
    gemm_bt<64, 1, 0, 1, 1><<<dim3(8, 64), 256, 0, stream>>>(
        QKV, QKVLD, WoT, En, bo, x, X1, En, En);

    // 5. late weight transposes (QKV region + WT region now dead)
    transpose_w<<<dim3(64, 16), 256, 0, stream>>>(W1, W1T, 1024, 4096);
    transpose_w<<<dim3(16, 64), 256, 0, stream>>>(W2, W2T, 4096, 1024);

    // 6. h2 = LN(X1, g2, be2)
    ln_kernel<<<Mn, 256, 0, stream>>>(X1, g2, be2, h);

    // 7. FFN in 2 halves of 2048; X1 accumulates in place; final -> d_out fp32
    gemm_bt<128, 1, 1, 0, 0><<<dim3(16, 32), 256, 0, stream>>>(
        h, En, W1T, En, b1, nullptr, F1, 2048, En);
    gemm_bt<64, 0, 0, 1, 1><<<dim3(8, 64), 256, 0, stream>>>(
        F1, 2048, W2T, DFFn, nullptr, X1, X1, En, 2048);
    gemm_bt<128, 1, 1, 0, 0><<<dim3(16, 32), 256, 0, stream>>>(
        h, En, W1T + 2048u * 1024, En, b1 + 2048, nullptr, F1, 2048, En);
    gemm_bt<64, 1, 0, 1, 1><<<dim3(8, 64), 256, 0, stream>>>(
        F1, 2048, W2T + 2048, DFFn, b2, X1, (float*)d_out, En, 2048);
}

// Round 8
// 406.616 us; speedup vs baseline: 11.1445x; 1.2735x over previous
//
#include <hip/hip_runtime.h>
#include <hip/hip_bf16.h>
#include <math.h>

// Problem constants
#define Bn 2
#define Tn 2048
#define En 1024
#define Hn 16
#define DFFn 4096
#define Mn (Bn*Tn)   // 4096 rows
#define QKVLD 3072   // fused QKV leading dim

typedef __hip_bfloat16 bf16;
typedef unsigned short u16;
typedef __attribute__((ext_vector_type(8))) short short8;
typedef __attribute__((ext_vector_type(4))) float f32x4;

typedef __attribute__((address_space(1))) const void cg_void;
typedef __attribute__((address_space(3))) void lds_void;

__device__ __forceinline__ u16 f2bf(float f) {
    bf16 h = __float2bfloat16(f);
    u16 u; __builtin_memcpy(&u, &h, 2); return u;
}

// ---------------- weight transpose+convert: src fp32 [R][C] -> dst bf16 [C][R]
__global__ __launch_bounds__(256)
void transpose_w(const float* __restrict__ src, u16* __restrict__ dst,
                 int R, int C) {
    __shared__ float t[64][65];
    const int r0 = blockIdx.y * 64, c0 = blockIdx.x * 64;
    const int tr = threadIdx.x >> 6, tc = threadIdx.x & 63;
#pragma unroll
    for (int i = 0; i < 16; i++)
        t[tr + i * 4][tc] = src[(size_t)(r0 + tr + i * 4) * C + c0 + tc];
    __syncthreads();
#pragma unroll
    for (int i = 0; i < 16; i++)
        dst[(size_t)(c0 + tr + i * 4) * R + r0 + tc] = f2bf(t[tc][tr + i * 4]);
}

// ---------------- LayerNorm: one block per row of E=1024 ---------------------
__global__ __launch_bounds__(256)
void ln_kernel(const float* __restrict__ x, const float* __restrict__ g,
               const float* __restrict__ b, u16* __restrict__ out) {
    const int row = blockIdx.x;
    const int tid = threadIdx.x;
    const float* xp = x + (size_t)row * En;
    float v[4];
    float s = 0.f, sq = 0.f;
#pragma unroll
    for (int i = 0; i < 4; i++) {
        v[i] = xp[tid + i * 256];
        s += v[i];
        sq += v[i] * v[i];
    }
    __shared__ float rs[256], rq[256];
    rs[tid] = s; rq[tid] = sq;
    __syncthreads();
    for (int st = 128; st > 0; st >>= 1) {
        if (tid < st) { rs[tid] += rs[tid + st]; rq[tid] += rq[tid + st]; }
        __syncthreads();
    }
    const float mu  = rs[0] * (1.0f / En);
    const float var = rq[0] * (1.0f / En) - mu * mu;
    const float inv = rsqrtf(var + 1e-5f);
#pragma unroll
    for (int i = 0; i < 4; i++) {
        const int c = tid + i * 256;
        out[(size_t)row * En + c] = f2bf((v[i] - mu) * inv * g[c] + b[c]);
    }
}

// ---------------- m97-style GEMM: C[4096,N] = A(bf16) @ Wt(bf16 [N][K])^T ----
// TM x 128 tile (TM = 128 or 64), BK=32, 4 waves. global_load_lds width=16
// staging into unpadded [rows][32] LDS (lane-contiguous per m104/m108 rule).
template<int TM, int HAS_BIAS, int RELU, int HAS_RES, int OUT_F32>
__global__ __launch_bounds__(256)
void gemm_bt(const u16* __restrict__ A, int ldA,
             const u16* __restrict__ Wt, int ldW,
             const float* __restrict__ bias, const float* __restrict__ res,
             void* __restrict__ Cout, int ldC, int Kd) {
    constexpr int IF = TM / 32;          // i-frags per wave
    __shared__ __align__(16) u16 As[TM * 32];
    __shared__ __align__(16) u16 Bs[128 * 32];
    const int tid  = threadIdx.x;
    const int lane = tid & 63, wv = tid >> 6;
    const int quad = lane >> 4, l16 = lane & 15;
    const int m0 = blockIdx.y * TM, n0 = blockIdx.x * 128;
    const int rw = (wv >> 1) * (TM / 2), cw = (wv & 1) * 64;
    const int lr = lane >> 2, lc = (lane & 3) * 8;   // staging lane row/colgrp

    f32x4 acc[IF][4] = {};

    for (int kt = 0; kt < Kd; kt += 32) {
        __syncthreads();   // previous iteration's LDS readers done
        // A tile TM x 32: each wave-instr = 16 rows x 64 B, lane L -> L*16 B
#pragma unroll
        for (int t = 0; t < TM / 64; t++) {
            const int row = wv * (TM / 4) + t * 16;
            __builtin_amdgcn_global_load_lds(
                (cg_void*)(const void*)&A[(size_t)(m0 + row + lr) * ldA + kt + lc],
                (lds_void*)(void*)&As[row * 32], 16, 0, 0);
        }
        // B tile 128 x 32 from Wt [N][K]
#pragma unroll
        for (int t = 0; t < 2; t++) {
            const int row = wv * 32 + t * 16;
            __builtin_amdgcn_global_load_lds(
                (cg_void*)(const void*)&Wt[(size_t)(n0 + row + lr) * ldW + kt + lc],
                (lds_void*)(void*)&Bs[row * 32], 16, 0, 0);
        }
        __syncthreads();   // compiler emits vmcnt(0) drain before barrier

        short8 af[IF], bfr[4];
#pragma unroll
        for (int i = 0; i < IF; i++)
            af[i] = *(const short8*)&As[(rw + i * 16 + l16) * 32 + quad * 8];
#pragma unroll
        for (int j = 0; j < 4; j++)
            bfr[j] = *(const short8*)&Bs[(cw + j * 16 + l16) * 32 + quad * 8];
#pragma unroll
        for (int i = 0; i < IF; i++)
#pragma unroll
            for (int j = 0; j < 4; j++)
                acc[i][j] = __builtin_amdgcn_mfma_f32_16x16x32_bf16(
                    af[i], bfr[j], acc[i][j], 0, 0, 0);
    }

    // Epilogue. C/D layout: row = quad*4+r, col = l16 (m89-verified).
#pragma unroll
    for (int i = 0; i < IF; i++) {
#pragma unroll
        for (int r = 0; r < 4; r++) {
            const int gm = m0 + rw + i * 16 + quad * 4 + r;
#pragma unroll
            for (int j = 0; j < 4; j++) {
                const int gn = n0 + cw + j * 16 + l16;
                float c = acc[i][j][r];
                if (HAS_BIAS) c += bias[gn];
                if (RELU) c = fmaxf(c, 0.f);
                if (HAS_RES) c += res[(size_t)gm * ldC + gn];
                if (OUT_F32) ((float*)Cout)[(size_t)gm * ldC + gn] = c;
                else         ((u16*)Cout)[(size_t)gm * ldC + gn] = f2bf(c);
            }
        }
    }
}

// ---------------- Flash attention v3 ----------------------------------------
// Transposed-S form: S^T = K Q^T, O^T = V^T P^T (operand swaps; same LDS reads).
// Row stats (m,l) are per-lane (q = l16): 2 shfl_xor per reduction, alpha
// rescale lane-local. Register prefetch of next K/V tile overlaps global
// latency with compute. Paired q-tiles {x, 31-x}: uniform 33 iters/block.
// QKV [4096][3072] bf16: Q@0, K@1024, V@2048. O in-place over Q.
__global__ __launch_bounds__(256)
void flash_attn(u16* __restrict__ QKV) {
    const int hh = blockIdx.y, bb = blockIdx.z;
    const int tid  = threadIdx.x;
    const int lane = tid & 63, wv = tid >> 6;
    const int quad = lane >> 4, l16 = lane & 15;

    __shared__ __align__(16) u16 Qs[64 * 80];
    __shared__ __align__(16) u16 Ks[64 * 80];
    __shared__ __align__(16) u16 Vt[64 * 80];       // [dh][key]
    __shared__ __align__(16) u16 Ps[4][16 * 70];    // [q][key], stride 70

    const size_t rowbase = (size_t)(bb * Tn) * QKVLD;
    const int sr = tid >> 2, scg = tid & 3;         // Q/K staging
    const int vkey = tid & 63, vw = tid >> 6;       // V staging: lane = key
    const float SC = 0.03125f * 1.44269504089f;     // E^-0.5 * log2(e)

    for (int qsel = 0; qsel < 2; qsel++) {
        const int qt = qsel ? (31 - blockIdx.x) : blockIdx.x;

        __syncthreads();   // all readers of previous q-tile's Qs/Ks/Vt done
        {   // stage Q tile 64x64
            const size_t qb = rowbase + (size_t)(qt * 64 + sr) * QKVLD + hh * 64;
            *(uint4*)&Qs[sr * 80 + scg * 8]       = *(const uint4*)&QKV[qb + scg * 8];
            *(uint4*)&Qs[sr * 80 + (scg + 4) * 8] = *(const uint4*)&QKV[qb + (scg + 4) * 8];
        }
        // preload K/V tile kt=0 into registers
        uint4 kreg0, kreg1, vreg0, vreg1;
        {
            const size_t kb = rowbase + (size_t)(sr) * QKVLD + 1024 + hh * 64;
            kreg0 = *(const uint4*)&QKV[kb + scg * 8];
            kreg1 = *(const uint4*)&QKV[kb + (scg + 4) * 8];
            const size_t vb = rowbase + (size_t)(vkey) * QKVLD + 2048 + hh * 64 + vw * 16;
            vreg0 = *(const uint4*)&QKV[vb];
            vreg1 = *(const uint4*)&QKV[vb + 8];
        }
        __syncthreads();   // Qs ready
        short8 qf[2];
        qf[0] = *(const short8*)&Qs[(wv * 16 + l16) * 80 + quad * 8];
        qf[1] = *(const short8*)&Qs[(wv * 16 + l16) * 80 + 32 + quad * 8];

        f32x4 ot[4] = {};                 // O^T: [i][r] -> dh=i*16+quad*4+r, q=l16
        float m2 = -INFINITY, lrow = 0.f; // per-lane state for q = strip + l16

        for (int kt = 0; kt <= qt; kt++) {
            __syncthreads();   // previous iteration's Ks/Vt readers done
            {   // write prefetched K tile (row-major) and V tile (transposed)
                *(uint4*)&Ks[sr * 80 + scg * 8]       = kreg0;
                *(uint4*)&Ks[sr * 80 + (scg + 4) * 8] = kreg1;
                u16 vtmp[16];
                *(uint4*)&vtmp[0] = vreg0;
                *(uint4*)&vtmp[8] = vreg1;
#pragma unroll
                for (int u = 0; u < 16; u++)
                    Vt[(vw * 16 + u) * 80 + vkey] = vtmp[u];
            }
            if (kt < qt) {   // prefetch kt+1 (uniform branch)
                const size_t kb = rowbase + (size_t)((kt + 1) * 64 + sr) * QKVLD + 1024 + hh * 64;
                kreg0 = *(const uint4*)&QKV[kb + scg * 8];
                kreg1 = *(const uint4*)&QKV[kb + (scg + 4) * 8];
                const size_t vb = rowbase + (size_t)((kt + 1) * 64 + vkey) * QKVLD + 2048 + hh * 64 + vw * 16;
                vreg0 = *(const uint4*)&QKV[vb];
                vreg1 = *(const uint4*)&QKV[vb + 8];
            }
            __syncthreads();   // Ks/Vt ready

            // S^T strip: St[key=i*16+quad*4+r][q=l16], 64 keys x 16 q
            f32x4 st[4] = {};
#pragma unroll
            for (int ks = 0; ks < 2; ks++)
#pragma unroll
                for (int i = 0; i < 4; i++) {
                    short8 kf = *(const short8*)&Ks[(i * 16 + l16) * 80 + ks * 32 + quad * 8];
                    st[i] = __builtin_amdgcn_mfma_f32_16x16x32_bf16(kf, qf[ks], st[i], 0, 0, 0);
                }

            // per-lane online softmax over this lane's 16 keys (log2 domain)
            float p[4][4];
            float tmax = -INFINITY;
            if (kt == qt) {                       // diagonal: causal mask
                const int qloc = wv * 16 + l16;
#pragma unroll
                for (int i = 0; i < 4; i++)
#pragma unroll
                    for (int r = 0; r < 4; r++) {
                        float s = st[i][r] * SC;
                        if (i * 16 + quad * 4 + r > qloc) s = -INFINITY;
                        p[i][r] = s;
                        tmax = fmaxf(tmax, s);
                    }
            } else {
#pragma unroll
                for (int i = 0; i < 4; i++)
#pragma unroll
                    for (int r = 0; r < 4; r++) {
                        const float s = st[i][r] * SC;
                        p[i][r] = s;
                        tmax = fmaxf(tmax, s);
                    }
            }
            tmax = fmaxf(tmax, __shfl_xor(tmax, 16));
            tmax = fmaxf(tmax, __shfl_xor(tmax, 32));

            const float mnew = fmaxf(m2, tmax);
            const float alpha = exp2f(m2 - mnew);   // first iter: exp2(-inf)=0
            m2 = mnew;
            float psum = 0.f;
#pragma unroll
            for (int i = 0; i < 4; i++)
#pragma unroll
                for (int r = 0; r < 4; r++) {
                    const float e = exp2f(p[i][r] - mnew);
                    p[i][r] = e;
                    psum += e;
                }
            psum += __shfl_xor(psum, 16);
            psum += __shfl_xor(psum, 32);
            lrow = lrow * alpha + psum;
#pragma unroll
            for (int i = 0; i < 4; i++) ot[i] *= alpha;   // lane-local rescale

            // P^T (C-layout) -> Ps[q][key] row-major
#pragma unroll
            for (int i = 0; i < 4; i++)
#pragma unroll
                for (int r = 0; r < 4; r++)
                    Ps[wv][l16 * 70 + i * 16 + quad * 4 + r] = f2bf(p[i][r]);
            asm volatile("s_waitcnt lgkmcnt(0)" ::: "memory");

            // O^T strip += V^T @ P^T
#pragma unroll
            for (int ks = 0; ks < 2; ks++) {
                short8 pf = *(const short8*)&Ps[wv][l16 * 70 + ks * 32 + quad * 8];
#pragma unroll
                for (int i = 0; i < 4; i++) {
                    short8 vf = *(const short8*)&Vt[(i * 16 + l16) * 80 + ks * 32 + quad * 8];
                    ot[i] = __builtin_amdgcn_mfma_f32_16x16x32_bf16(vf, pf, ot[i], 0, 0, 0);
                }
            }
        }

        // write O over Q slice: lane holds q = strip+l16, dh = i*16+quad*4+r
        const float linv = 1.0f / lrow;
        const size_t obase = rowbase + (size_t)(qt * 64 + wv * 16 + l16) * QKVLD + hh * 64;
#pragma unroll
        for (int i = 0; i < 4; i++)
#pragma unroll
            for (int r = 0; r < 4; r++)
                QKV[obase + i * 16 + quad * 4 + r] = f2bf(ot[i][r] * linv);
    }
}

// ---------------- Launcher ---------------------------------------------------
// Inputs fp32, output fp32 [B,T,E].
extern "C" void kernel_launch(void* const* d_in, const int* in_sizes, int n_in,
                              void* d_out, int out_size, void* d_ws, size_t ws_size,
                              hipStream_t stream) {
    const float* x   = (const float*)d_in[0];
    const float* Wq  = (const float*)d_in[1];
    const float* Wk  = (const float*)d_in[2];
    const float* Wv  = (const float*)d_in[3];
    const float* Wo  = (const float*)d_in[4];
    const float* bo  = (const float*)d_in[5];
    const float* W1  = (const float*)d_in[6];
    const float* b1  = (const float*)d_in[7];
    const float* W2  = (const float*)d_in[8];
    const float* b2  = (const float*)d_in[9];
    const float* g1  = (const float*)d_in[10];
    const float* be1 = (const float*)d_in[11];
    const float* g2  = (const float*)d_in[12];
    const float* be2 = (const float*)d_in[13];

    // Workspace (40 MB):
    //   [ 0,24M): QKV bf16 [4096][3072]; dead after O-proj -> F1 [0,16M),
    //             W2T bf16 [1024][4096] at [16,24M)
    //   [24,40M): X1 fp32 [4096][1024]
    // d_out (16 MB fp32): [0,8M) h bf16; [8,16M) early WqkvT+WoT, late W1T.
    char* wsb = (char*)d_ws;
    u16*   QKV = (u16*)wsb;
    u16*   F1  = (u16*)wsb;                              // [4096][2048]
    u16*   W2T = (u16*)(wsb + 16u * 1024 * 1024);        // [1024][4096]
    float* X1  = (float*)(wsb + 24u * 1024 * 1024);
    u16*   h     = (u16*)d_out;
    u16*   WT    = (u16*)((char*)d_out + 8u * 1024 * 1024);
    u16*   WqkvT = WT;                                   // [3072][1024]
    u16*   WoT   = WT + 3u * 1024 * 1024;                // [1024][1024]
    u16*   W1T   = WT;                                   // [4096][1024] (late)

    // 0. early weight transposes (fp32 -> bf16, B^T layout)
    transpose_w<<<dim3(16, 16), 256, 0, stream>>>(Wq, WqkvT,                 1024, 1024);
    transpose_w<<<dim3(16, 16), 256, 0, stream>>>(Wk, WqkvT + 1024u * 1024,  1024, 1024);
    transpose_w<<<dim3(16, 16), 256, 0, stream>>>(Wv, WqkvT + 2048u * 1024,  1024, 1024);
    transpose_w<<<dim3(16, 16), 256, 0, stream>>>(Wo, WoT,                   1024, 1024);

    // 1. h = LN(x, g1, be1)
    ln_kernel<<<Mn, 256, 0, stream>>>(x, g1, be1, h);

    // 2. QKV = h @ [Wq|Wk|Wv]  (one fused GEMM, N=3072, 768 blocks)
    gemm_bt<128, 0, 0, 0, 0><<<dim3(24, 32), 256, 0, stream>>>(
        h, En, WqkvT, En, nullptr, nullptr, QKV, QKVLD, En);

    // 3. O = causal_softmax(Q K^T * E^-0.5) V   (in place over Q cols)
    flash_attn<<<dim3(16, Hn, Bn), 256, 0, stream>>>(QKV);

    // 4. X1 = x + O @ Wo + bo   (fp32; TM=64 -> 512 blocks)
    gemm_bt<64, 1, 0, 1, 1><<<dim3(8, 64), 256, 0, stream>>>(
        QKV, QKVLD, WoT, En, bo, x, X1, En, En);

    // 5. late weight transposes (QKV region + WT region now dead)
    transpose_w<<<dim3(64, 16), 256, 0, stream>>>(W1, W1T, 1024, 4096);
    transpose_w<<<dim3(16, 64), 256, 0, stream>>>(W2, W2T, 4096, 1024);

    // 6. h2 = LN(X1, g2, be2)
    ln_kernel<<<Mn, 256, 0, stream>>>(X1, g2, be2, h);

    // 7. FFN in 2 halves of 2048; X1 accumulates in place; final -> d_out fp32
    gemm_bt<128, 1, 1, 0, 0><<<dim3(16, 32), 256, 0, stream>>>(
        h, En, W1T, En, b1, nullptr, F1, 2048, En);
    gemm_bt<64, 0, 0, 1, 1><<<dim3(8, 64), 256, 0, stream>>>(
        F1, 2048, W2T, DFFn, nullptr, X1, X1, En, 2048);
    gemm_bt<128, 1, 1, 0, 0><<<dim3(16, 32), 256, 0, stream>>>(
        h, En, W1T + 2048u * 1024, En, b1 + 2048, nullptr, F1, 2048, En);
    gemm_bt<64, 1, 0, 1, 1><<<dim3(8, 64), 256, 0, stream>>>(
        F1, 2048, W2T + 2048, DFFn, b2, X1, (float*)d_out, En, 2048);
}

// Round 9
// 393.911 us; speedup vs baseline: 11.5040x; 1.0323x over previous
//
#include <hip/hip_runtime.h>
#include <hip/hip_bf16.h>
#include <math.h>

// Problem constants
#define Bn 2
#define Tn 2048
#define En 1024
#define Hn 16
#define DFFn 4096
#define Mn (Bn*Tn)   // 4096 rows
#define QKVLD 3072   // fused QKV leading dim

typedef __hip_bfloat16 bf16;
typedef unsigned short u16;
typedef __attribute__((ext_vector_type(8))) short short8;
typedef __attribute__((ext_vector_type(4))) float f32x4;

typedef __attribute__((address_space(1))) const void cg_void;
typedef __attribute__((address_space(3))) void lds_void;

// lgkm-only barrier: LDS writes visible + wave sync, but vmcnt (global loads
// in flight to REGISTERS, wave-private) is NOT drained -- this is the whole
// point: register prefetches survive the barrier.
#define HBAR() asm volatile("s_waitcnt lgkmcnt(0)\n\ts_barrier" ::: "memory")

__device__ __forceinline__ u16 f2bf(float f) {
    bf16 h = __float2bfloat16(f);
    u16 u; __builtin_memcpy(&u, &h, 2); return u;
}

// ---------------- 4x weight transpose+convert (1024x1024 each) ---------------
__global__ __launch_bounds__(256)
void transpose_w4(const float* __restrict__ s0, const float* __restrict__ s1,
                  const float* __restrict__ s2, const float* __restrict__ s3,
                  u16* __restrict__ d0, u16* __restrict__ d1,
                  u16* __restrict__ d2, u16* __restrict__ d3) {
    const float* src = (blockIdx.z == 0) ? s0 : (blockIdx.z == 1) ? s1
                     : (blockIdx.z == 2) ? s2 : s3;
    u16* dst = (blockIdx.z == 0) ? d0 : (blockIdx.z == 1) ? d1
             : (blockIdx.z == 2) ? d2 : d3;
    __shared__ float t[64][65];
    const int r0 = blockIdx.y * 64, c0 = blockIdx.x * 64;
    const int tr = threadIdx.x >> 6, tc = threadIdx.x & 63;
#pragma unroll
    for (int i = 0; i < 16; i++)
        t[tr + i * 4][tc] = src[(size_t)(r0 + tr + i * 4) * 1024 + c0 + tc];
    __syncthreads();
#pragma unroll
    for (int i = 0; i < 16; i++)
        dst[(size_t)(c0 + tr + i * 4) * 1024 + r0 + tc] = f2bf(t[tc][tr + i * 4]);
}

// ---------------- generic weight transpose: src fp32 [R][C] -> bf16 [C][R] ---
__global__ __launch_bounds__(256)
void transpose_w(const float* __restrict__ src, u16* __restrict__ dst,
                 int R, int C) {
    __shared__ float t[64][65];
    const int r0 = blockIdx.y * 64, c0 = blockIdx.x * 64;
    const int tr = threadIdx.x >> 6, tc = threadIdx.x & 63;
#pragma unroll
    for (int i = 0; i < 16; i++)
        t[tr + i * 4][tc] = src[(size_t)(r0 + tr + i * 4) * C + c0 + tc];
    __syncthreads();
#pragma unroll
    for (int i = 0; i < 16; i++)
        dst[(size_t)(c0 + tr + i * 4) * R + r0 + tc] = f2bf(t[tc][tr + i * 4]);
}

// ---------------- LayerNorm: one block per row of E=1024 ---------------------
__global__ __launch_bounds__(256)
void ln_kernel(const float* __restrict__ x, const float* __restrict__ g,
               const float* __restrict__ b, u16* __restrict__ out) {
    const int row = blockIdx.x;
    const int tid = threadIdx.x;
    const float* xp = x + (size_t)row * En;
    float v[4];
    float s = 0.f, sq = 0.f;
#pragma unroll
    for (int i = 0; i < 4; i++) {
        v[i] = xp[tid + i * 256];
        s += v[i];
        sq += v[i] * v[i];
    }
    __shared__ float rs[256], rq[256];
    rs[tid] = s; rq[tid] = sq;
    __syncthreads();
    for (int st = 128; st > 0; st >>= 1) {
        if (tid < st) { rs[tid] += rs[tid + st]; rq[tid] += rq[tid + st]; }
        __syncthreads();
    }
    const float mu  = rs[0] * (1.0f / En);
    const float var = rq[0] * (1.0f / En) - mu * mu;
    const float inv = rsqrtf(var + 1e-5f);
#pragma unroll
    for (int i = 0; i < 4; i++) {
        const int c = tid + i * 256;
        out[(size_t)row * En + c] = f2bf((v[i] - mu) * inv * g[c] + b[c]);
    }
}

// ---------------- m97-style GEMM + XOR swizzle -------------------------------
// C[4096,N] = A(bf16 [M][K]) @ Wt(bf16 [N][K])^T. TM x 128 tile, BK=32, 4 waves.
// LDS layout [row][32] unpadded (global_load_lds lane rule) with XOR swizzle:
// logical colgroup g (8 shorts) of row r stored at physical g ^ ((r>>1)&3).
// Writer picks the global source per lane (coalescing preserved: permutation
// stays within one 64-B row). ds_read_b128 banks become 2-way (free) vs 8-way.
template<int TM, int HAS_BIAS, int RELU, int HAS_RES, int OUT_F32>
__global__ __launch_bounds__(256)
void gemm_bt(const u16* __restrict__ A, int ldA,
             const u16* __restrict__ Wt, int ldW,
             const float* __restrict__ bias, const float* __restrict__ res,
             void* __restrict__ Cout, int ldC, int Kd) {
    constexpr int IF = TM / 32;          // i-frags per wave
    __shared__ __align__(16) u16 As[TM * 32];
    __shared__ __align__(16) u16 Bs[128 * 32];
    const int tid  = threadIdx.x;
    const int lane = tid & 63, wv = tid >> 6;
    const int quad = lane >> 4, l16 = lane & 15;
    const int m0 = blockIdx.y * TM, n0 = blockIdx.x * 128;
    const int rw = (wv >> 1) * (TM / 2), cw = (wv & 1) * 64;
    const int lr  = lane >> 2;                         // row within 16-row chunk
    const int gsw = ((lane & 3) ^ ((lane >> 3) & 3)) * 8;  // swizzled src colgrp
    const int psw = (quad ^ ((l16 >> 1) & 3)) * 8;     // swizzled read colgrp

    f32x4 acc[IF][4] = {};

    for (int kt = 0; kt < Kd; kt += 32) {
        __syncthreads();   // previous iteration's LDS readers done
#pragma unroll
        for (int t = 0; t < TM / 64; t++) {
            const int row = wv * (TM / 4) + t * 16;
            __builtin_amdgcn_global_load_lds(
                (cg_void*)(const void*)&A[(size_t)(m0 + row + lr) * ldA + kt + gsw],
                (lds_void*)(void*)&As[row * 32], 16, 0, 0);
        }
#pragma unroll
        for (int t = 0; t < 2; t++) {
            const int row = wv * 32 + t * 16;
            __builtin_amdgcn_global_load_lds(
                (cg_void*)(const void*)&Wt[(size_t)(n0 + row + lr) * ldW + kt + gsw],
                (lds_void*)(void*)&Bs[row * 32], 16, 0, 0);
        }
        __syncthreads();

        short8 af[IF], bfr[4];
#pragma unroll
        for (int i = 0; i < IF; i++)
            af[i] = *(const short8*)&As[(rw + i * 16 + l16) * 32 + psw];
#pragma unroll
        for (int j = 0; j < 4; j++)
            bfr[j] = *(const short8*)&Bs[(cw + j * 16 + l16) * 32 + psw];
#pragma unroll
        for (int i = 0; i < IF; i++)
#pragma unroll
            for (int j = 0; j < 4; j++)
                acc[i][j] = __builtin_amdgcn_mfma_f32_16x16x32_bf16(
                    af[i], bfr[j], acc[i][j], 0, 0, 0);
    }

    // Epilogue. C/D layout: row = quad*4+r, col = l16 (m89-verified).
#pragma unroll
    for (int i = 0; i < IF; i++) {
#pragma unroll
        for (int r = 0; r < 4; r++) {
            const int gm = m0 + rw + i * 16 + quad * 4 + r;
#pragma unroll
            for (int j = 0; j < 4; j++) {
                const int gn = n0 + cw + j * 16 + l16;
                float c = acc[i][j][r];
                if (HAS_BIAS) c += bias[gn];
                if (RELU) c = fmaxf(c, 0.f);
                if (HAS_RES) c += res[(size_t)gm * ldC + gn];
                if (OUT_F32) ((float*)Cout)[(size_t)gm * ldC + gn] = c;
                else         ((u16*)Cout)[(size_t)gm * ldC + gn] = f2bf(c);
            }
        }
    }
}

// ---------------- Flash attention v4 -----------------------------------------
// Transposed-S (per-lane q stats), K/V double-buffered in LDS, ONE lgkm-only
// hand barrier per iter so register prefetches stay in flight across it.
// Paired q-tiles {x, 31-x}: uniform 33 iters/block. O in-place over Q.
__global__ __launch_bounds__(256)
void flash_attn(u16* __restrict__ QKV) {
    const int hh = blockIdx.y, bb = blockIdx.z;
    const int tid  = threadIdx.x;
    const int lane = tid & 63, wv = tid >> 6;
    const int quad = lane >> 4, l16 = lane & 15;

    __shared__ __align__(16) u16 Qs[64 * 88];       // stride 88: 2-way banks
    __shared__ __align__(16) u16 Ks[2][64 * 88];
    __shared__ __align__(16) u16 Vt[2][64 * 88];    // [dh][key]
    __shared__ __align__(16) u16 Ps[4][16 * 70];    // [q][key]

    const size_t rowbase = (size_t)(bb * Tn) * QKVLD;
    const int sr = tid >> 2, scg = tid & 3;         // Q/K staging
    const int vkey = tid & 63, vw = tid >> 6;       // V staging: lane = key
    const float SC = 0.03125f * 1.44269504089f;     // E^-0.5 * log2(e)

    for (int qsel = 0; qsel < 2; qsel++) {
        const int qt = qsel ? (31 - blockIdx.x) : blockIdx.x;

        HBAR();   // previous q-tile's LDS readers done
        {   // stage Q tile 64x64
            const size_t qb = rowbase + (size_t)(qt * 64 + sr) * QKVLD + hh * 64;
            *(uint4*)&Qs[sr * 88 + scg * 8]       = *(const uint4*)&QKV[qb + scg * 8];
            *(uint4*)&Qs[sr * 88 + (scg + 4) * 8] = *(const uint4*)&QKV[qb + (scg + 4) * 8];
        }
        // load K/V tile 0 and stage into buffer 0
        uint4 kreg0, kreg1, vreg0, vreg1;
        {
            const size_t kb = rowbase + (size_t)sr * QKVLD + 1024 + hh * 64;
            kreg0 = *(const uint4*)&QKV[kb + scg * 8];
            kreg1 = *(const uint4*)&QKV[kb + (scg + 4) * 8];
            const size_t vb = rowbase + (size_t)vkey * QKVLD + 2048 + hh * 64 + vw * 16;
            vreg0 = *(const uint4*)&QKV[vb];
            vreg1 = *(const uint4*)&QKV[vb + 8];
            *(uint4*)&Ks[0][sr * 88 + scg * 8]       = kreg0;
            *(uint4*)&Ks[0][sr * 88 + (scg + 4) * 8] = kreg1;
            u16 vtmp[16];
            *(uint4*)&vtmp[0] = vreg0;
            *(uint4*)&vtmp[8] = vreg1;
#pragma unroll
            for (int u = 0; u < 16; u++)
                Vt[0][(vw * 16 + u) * 88 + vkey] = vtmp[u];
        }
        if (qt >= 1) {   // prefetch tile 1 (stays outstanding across HBAR)
            const size_t kb = rowbase + (size_t)(64 + sr) * QKVLD + 1024 + hh * 64;
            kreg0 = *(const uint4*)&QKV[kb + scg * 8];
            kreg1 = *(const uint4*)&QKV[kb + (scg + 4) * 8];
            const size_t vb = rowbase + (size_t)(64 + vkey) * QKVLD + 2048 + hh * 64 + vw * 16;
            vreg0 = *(const uint4*)&QKV[vb];
            vreg1 = *(const uint4*)&QKV[vb + 8];
        }
        HBAR();   // Qs + buf0 visible
        short8 qf[2];
        qf[0] = *(const short8*)&Qs[(wv * 16 + l16) * 88 + quad * 8];
        qf[1] = *(const short8*)&Qs[(wv * 16 + l16) * 88 + 32 + quad * 8];

        f32x4 ot[4] = {};                 // O^T: dh=i*16+quad*4+r, q=l16
        float m2 = -INFINITY, lrow = 0.f;

        for (int kt = 0; kt <= qt; kt++) {
            const int cur = kt & 1;

            // S^T strip: St[key=i*16+quad*4+r][q=l16]
            f32x4 st[4] = {};
#pragma unroll
            for (int ks = 0; ks < 2; ks++)
#pragma unroll
                for (int i = 0; i < 4; i++) {
                    short8 kf = *(const short8*)&Ks[cur][(i * 16 + l16) * 88 + ks * 32 + quad * 8];
                    st[i] = __builtin_amdgcn_mfma_f32_16x16x32_bf16(kf, qf[ks], st[i], 0, 0, 0);
                }

            // per-lane online softmax (log2 domain)
            float p[4][4];
            float tmax = -INFINITY;
            if (kt == qt) {                       // diagonal: causal mask
                const int qloc = wv * 16 + l16;
#pragma unroll
                for (int i = 0; i < 4; i++)
#pragma unroll
                    for (int r = 0; r < 4; r++) {
                        float s = st[i][r] * SC;
                        if (i * 16 + quad * 4 + r > qloc) s = -INFINITY;
                        p[i][r] = s;
                        tmax = fmaxf(tmax, s);
                    }
            } else {
#pragma unroll
                for (int i = 0; i < 4; i++)
#pragma unroll
                    for (int r = 0; r < 4; r++) {
                        const float s = st[i][r] * SC;
                        p[i][r] = s;
                        tmax = fmaxf(tmax, s);
                    }
            }
            tmax = fmaxf(tmax, __shfl_xor(tmax, 16));
            tmax = fmaxf(tmax, __shfl_xor(tmax, 32));

            const float mnew = fmaxf(m2, tmax);
            const float alpha = exp2f(m2 - mnew);
            m2 = mnew;
            float psum = 0.f;
#pragma unroll
            for (int i = 0; i < 4; i++)
#pragma unroll
                for (int r = 0; r < 4; r++) {
                    const float e = exp2f(p[i][r] - mnew);
                    p[i][r] = e;
                    psum += e;
                }
            psum += __shfl_xor(psum, 16);
            psum += __shfl_xor(psum, 32);
            lrow = lrow * alpha + psum;
#pragma unroll
            for (int i = 0; i < 4; i++) ot[i] *= alpha;

            // P^T (C-layout) -> Ps[q][key] row-major (wave-private)
#pragma unroll
            for (int i = 0; i < 4; i++)
#pragma unroll
                for (int r = 0; r < 4; r++)
                    Ps[wv][l16 * 70 + i * 16 + quad * 4 + r] = f2bf(p[i][r]);
            asm volatile("s_waitcnt lgkmcnt(0)" ::: "memory");

            // O^T strip += V^T @ P^T
#pragma unroll
            for (int ks = 0; ks < 2; ks++) {
                short8 pf = *(const short8*)&Ps[wv][l16 * 70 + ks * 32 + quad * 8];
#pragma unroll
                for (int i = 0; i < 4; i++) {
                    short8 vf = *(const short8*)&Vt[cur][(i * 16 + l16) * 88 + ks * 32 + quad * 8];
                    ot[i] = __builtin_amdgcn_mfma_f32_16x16x32_bf16(vf, pf, ot[i], 0, 0, 0);
                }
            }

            if (kt < qt) {
                // write prefetched tile kt+1 into the other buffer
                // (vmcnt wait lands here, one full compute-phase after issue)
                *(uint4*)&Ks[cur ^ 1][sr * 88 + scg * 8]       = kreg0;
                *(uint4*)&Ks[cur ^ 1][sr * 88 + (scg + 4) * 8] = kreg1;
                u16 vtmp[16];
                *(uint4*)&vtmp[0] = vreg0;
                *(uint4*)&vtmp[8] = vreg1;
#pragma unroll
                for (int u = 0; u < 16; u++)
                    Vt[cur ^ 1][(vw * 16 + u) * 88 + vkey] = vtmp[u];
                if (kt + 1 < qt) {   // prefetch tile kt+2
                    const size_t kb = rowbase + (size_t)((kt + 2) * 64 + sr) * QKVLD + 1024 + hh * 64;
                    kreg0 = *(const uint4*)&QKV[kb + scg * 8];
                    kreg1 = *(const uint4*)&QKV[kb + (scg + 4) * 8];
                    const size_t vb = rowbase + (size_t)((kt + 2) * 64 + vkey) * QKVLD + 2048 + hh * 64 + vw * 16;
                    vreg0 = *(const uint4*)&QKV[vb];
                    vreg1 = *(const uint4*)&QKV[vb + 8];
                }
                HBAR();   // buf ready; prefetches stay in flight
            }
        }

        // write O over Q slice: q = wv*16+l16, dh = i*16+quad*4+r (ushort4 packed)
        const float linv = 1.0f / lrow;
        const size_t obase = rowbase + (size_t)(qt * 64 + wv * 16 + l16) * QKVLD + hh * 64;
#pragma unroll
        for (int i = 0; i < 4; i++) {
            ushort4 o4;
            o4.x = f2bf(ot[i][0] * linv);
            o4.y = f2bf(ot[i][1] * linv);
            o4.z = f2bf(ot[i][2] * linv);
            o4.w = f2bf(ot[i][3] * linv);
            *(ushort4*)&QKV[obase + i * 16 + quad * 4] = o4;
        }
    }
}

// ---------------- Launcher ---------------------------------------------------
// Inputs fp32, output fp32 [B,T,E].
extern "C" void kernel_launch(void* const* d_in, const int* in_sizes, int n_in,
                              void* d_out, int out_size, void* d_ws, size_t ws_size,
                              hipStream_t stream) {
    const float* x   = (const float*)d_in[0];
    const float* Wq  = (const float*)d_in[1];
    const float* Wk  = (const float*)d_in[2];
    const float* Wv  = (const float*)d_in[3];
    const float* Wo  = (const float*)d_in[4];
    const float* bo  = (const float*)d_in[5];
    const float* W1  = (const float*)d_in[6];
    const float* b1  = (const float*)d_in[7];
    const float* W2  = (const float*)d_in[8];
    const float* b2  = (const float*)d_in[9];
    const float* g1  = (const float*)d_in[10];
    const float* be1 = (const float*)d_in[11];
    const float* g2  = (const float*)d_in[12];
    const float* be2 = (const float*)d_in[13];

    // Workspace (40 MB):
    //   [ 0,24M): QKV bf16 [4096][3072]; dead after O-proj -> F1 [0,16M),
    //             W2T bf16 [1024][4096] at [16,24M)
    //   [24,40M): X1 fp32 [4096][1024]
    // d_out (16 MB fp32): [0,8M) h bf16; [8,16M) early WqkvT+WoT, late W1T.
    char* wsb = (char*)d_ws;
    u16*   QKV = (u16*)wsb;
    u16*   F1  = (u16*)wsb;                              // [4096][2048]
    u16*   W2T = (u16*)(wsb + 16u * 1024 * 1024);        // [1024][4096]
    float* X1  = (float*)(wsb + 24u * 1024 * 1024);
    u16*   h     = (u16*)d_out;
    u16*   WT    = (u16*)((char*)d_out + 8u * 1024 * 1024);
    u16*   WqkvT = WT;                                   // [3072][1024]
    u16*   WoT   = WT + 3u * 1024 * 1024;                // [1024][1024]
    u16*   W1T   = WT;                                   // [4096][1024] (late)

    // 0. early weight transposes (fp32 -> bf16, B^T layout) -- one dispatch
    transpose_w4<<<dim3(16, 16, 4), 256, 0, stream>>>(
        Wq, Wk, Wv, Wo,
        WqkvT, WqkvT + 1024u * 1024, WqkvT + 2048u * 1024, WoT);

    // 1. h = LN(x, g1, be1)
    ln_kernel<<<Mn, 256, 0, stream>>>(x, g1, be1, h);

    // 2. QKV = h @ [Wq|Wk|Wv]  (one fused GEMM, N=3072, 768 blocks)
    gemm_bt<128, 0, 0, 0, 0><<<dim3(24, 32), 256, 0, stream>>>(
        h, En, WqkvT, En, nullptr, nullptr, QKV, QKVLD, En);

    // 3. O = causal_softmax(Q K^T * E^-0.5) V   (in place over Q cols)
    flash_attn<<<dim3(16, Hn, Bn), 256, 0, stream>>>(QKV);

    // 4. X1 = x + O @ Wo + bo   (fp32; TM=64 -> 512 blocks)
    gemm_bt<64, 1, 0, 1, 1><<<dim3(8, 64), 256, 0, stream>>>(
        QKV, QKVLD, WoT, En, bo, x, X1, En, En);

    // 5. late weight transposes (QKV region + WT region now dead)
    transpose_w<<<dim3(64, 16), 256, 0, stream>>>(W1, W1T, 1024, 4096);
    transpose_w<<<dim3(16, 64), 256, 0, stream>>>(W2, W2T, 4096, 1024);

    // 6. h2 = LN(X1, g2, be2)
    ln_kernel<<<Mn, 256, 0, stream>>>(X1, g2, be2, h);

    // 7. FFN in 2 halves of 2048; X1 accumulates in place; final -> d_out fp32
    gemm_bt<128, 1, 1, 0, 0><<<dim3(16, 32), 256, 0, stream>>>(
        h, En, W1T, En, b1, nullptr, F1, 2048, En);
    gemm_bt<64, 0, 0, 1, 1><<<dim3(8, 64), 256, 0, stream>>>(
        F1, 2048, W2T, DFFn, nullptr, X1, X1, En, 2048);
    gemm_bt<128, 1, 1, 0, 0><<<dim3(16, 32), 256, 0, stream>>>(
        h, En, W1T + 2048u * 1024, En, b1 + 2048, nullptr, F1, 2048, En);
    gemm_bt<64, 1, 0, 1, 1><<<dim3(8, 64), 256, 0, stream>>>(
        F1, 2048, W2T + 2048, DFFn, b2, X1, (float*)d_out, En, 2048);
}